// Round 5
// baseline (1277.880 us; speedup 1.0000x reference)
//
#include <hip/hip_runtime.h>

#define B_ 16
#define N_ 4096
#define S_ 1024
#define K_ 32
#define R_ (B_*S_*K_)   // 524288 rows
#define NBLK_ (R_/64)   // 8192 row-tiles of 64

// max(key, dpp_move<CTRL>(key)) on a packed u64 key, identity-preserving.
template <int CTRL>
__device__ __forceinline__ unsigned long long dpp_max_u64(unsigned long long key) {
    int lo = (int)(unsigned)key;
    int hi = (int)(unsigned)(key >> 32);
    int olo = __builtin_amdgcn_update_dpp(lo, lo, CTRL, 0xF, 0xF, false);
    int ohi = __builtin_amdgcn_update_dpp(hi, hi, CTRL, 0xF, 0xF, false);
    unsigned long long other =
        ((unsigned long long)(unsigned)ohi << 32) | (unsigned)olo;
    return other > key ? other : key;
}

__device__ __forceinline__ unsigned long long packkey(double d, int idx) {
    unsigned long long bdd = (unsigned long long)__double_as_longlong(d);
    return (bdd & ~0xFFFull) | (unsigned)idx;
}

// ---------------------------------------------------------------- FPS
// one block per batch, 512 threads (8 waves), 8 points/thread.
// dist (f64, +1.0 biased) only decreases -> per-iter updates are sparse.
// f32 screen with margin picks the few slots needing the exact f64 update
// (skip => d64 >= dist64 guaranteed; fmin harmless for screened lanes).
// Wave-max key cached in SGPRs; the pack+tree+DPP butterfly reruns only when
// the wave's own cached winner updates (SALU check on ballot masks).
__global__ __launch_bounds__(512, 2) void fps_kernel(const float* __restrict__ xyz,
                                                     float* __restrict__ out0) {
    const int b = blockIdx.x;
    const int tid = threadIdx.x;
    const int lane = tid & 63, wid = tid >> 6;       // 8 waves
    __shared__ float4 p4[N_];
    __shared__ unsigned long long cand[2][8];
    const float* xb = xyz + (size_t)b * 3 * N_;

    float px[8], py[8], pz[8], q32[8], dmir[8];
    double q64[8], dist[8];
#pragma unroll
    for (int j = 0; j < 8; ++j) {
        int i = tid + j * 512;
        float x = xb[i], y = xb[N_ + i], z = xb[2 * N_ + i];
        p4[i] = make_float4(x, y, z, 0.f);
        px[j] = x; py[j] = y; pz[j] = z;
        double dx = (double)x, dy = (double)y, dz = (double)z;
        q64[j] = dx * dx + dy * dy + dz * dz;
        q32[j] = (float)q64[j];
        dist[j] = 1e30;
        dmir[j] = 1e30f;
    }
    __syncthreads();

    const float MARGIN = 1e-2f;
    unsigned long long ck = 0;       // cached wave-max key (uniform)
    bool valid = false;
    int far = 0;
    for (int s = 0; s < 1023; ++s) {
        float4 c = p4[far];
        if (tid == 0) {
            out0[(size_t)b * 3072 + s]        = c.x;
            out0[(size_t)b * 3072 + 1024 + s] = c.y;
            out0[(size_t)b * 3072 + 2048 + s] = c.z;
        }
        double cx = (double)c.x, cy = (double)c.y, cz = (double)c.z;
        double c2p = cx * cx + cy * cy + cz * cz + 1.0;
        double A = -2.0 * cx, Bq = -2.0 * cy, Cq = -2.0 * cz;
        float A32 = -2.0f * c.x, B32 = -2.0f * c.y, C32 = -2.0f * c.z;
        float D32 = (float)c2p;

        unsigned long long nm0, nm1, nm2, nm3, nm4, nm5, nm6, nm7;
#define FPS_STEP(J, NM)                                                        \
        {                                                                      \
            float d32 = fmaf(px[J], A32,                                       \
                        fmaf(py[J], B32,                                       \
                        fmaf(pz[J], C32, q32[J] + D32)));                      \
            NM = __ballot(d32 < dmir[J] + MARGIN);                             \
            dmir[J] = fminf(dmir[J], d32);                                     \
            if (NM) {                                                          \
                double d64 = fma(A, (double)px[J],                             \
                             fma(Bq, (double)py[J],                            \
                             fma(Cq, (double)pz[J], q64[J] + c2p)));           \
                dist[J] = fmin(dist[J], d64);                                  \
            }                                                                  \
        }
        FPS_STEP(0, nm0) FPS_STEP(1, nm1) FPS_STEP(2, nm2) FPS_STEP(3, nm3)
        FPS_STEP(4, nm4) FPS_STEP(5, nm5) FPS_STEP(6, nm6) FPS_STEP(7, nm7)
#undef FPS_STEP

        // does the wave's cached winner need a refresh?
        bool rec = !valid;
        if (valid) {
            int w_idx = (int)(ck & 0xFFFull);
            if (((w_idx & 511) >> 6) == wid) {
                int w_lane = w_idx & 63;
                int w_j = w_idx >> 9;
                unsigned long long nm;
                switch (w_j) {
                    case 0: nm = nm0; break; case 1: nm = nm1; break;
                    case 2: nm = nm2; break; case 3: nm = nm3; break;
                    case 4: nm = nm4; break; case 5: nm = nm5; break;
                    case 6: nm = nm6; break; default: nm = nm7; break;
                }
                rec = (nm >> w_lane) & 1ull;
            }
        }
        if (rec) {
            unsigned long long k0 = packkey(dist[0], tid);
            unsigned long long k1 = packkey(dist[1], tid + 512);
            unsigned long long k2l = packkey(dist[2], tid + 1024);
            unsigned long long k3 = packkey(dist[3], tid + 1536);
            unsigned long long k4 = packkey(dist[4], tid + 2048);
            unsigned long long k5 = packkey(dist[5], tid + 2560);
            unsigned long long k6 = packkey(dist[6], tid + 3072);
            unsigned long long k7 = packkey(dist[7], tid + 3584);
            k0 = k0 > k1 ? k0 : k1;   k2l = k2l > k3 ? k2l : k3;
            k4 = k4 > k5 ? k4 : k5;   k6 = k6 > k7 ? k6 : k7;
            k0 = k0 > k2l ? k0 : k2l; k4 = k4 > k6 ? k4 : k6;
            unsigned long long key = k0 > k4 ? k0 : k4;
            key = dpp_max_u64<0x111>(key);   // row_shr:1
            key = dpp_max_u64<0x112>(key);   // row_shr:2
            key = dpp_max_u64<0x114>(key);   // row_shr:4
            key = dpp_max_u64<0x118>(key);   // row_shr:8
            key = dpp_max_u64<0x142>(key);   // row_bcast15
            key = dpp_max_u64<0x143>(key);   // row_bcast31
            unsigned lo = (unsigned)__builtin_amdgcn_readlane((int)(unsigned)key, 63);
            unsigned hi = (unsigned)__builtin_amdgcn_readlane((int)(unsigned)(key >> 32), 63);
            ck = ((unsigned long long)hi << 32) | lo;
            valid = true;
        }
        int buf = s & 1;
        if (lane == 63) cand[buf][wid] = ck;
        __syncthreads();
        unsigned long long k2 = cand[buf][lane & 7];
        k2 = dpp_max_u64<0xB1>(k2);      // quad_perm xor1
        k2 = dpp_max_u64<0x4E>(k2);      // quad_perm xor2
        k2 = dpp_max_u64<0x124>(k2);     // row_ror:4
        far = (int)(__builtin_amdgcn_readfirstlane((unsigned)k2) & 0xFFFu);
    }
    if (tid == 0) {
        float4 c = p4[far];
        out0[(size_t)b * 3072 + 1023]        = c.x;
        out0[(size_t)b * 3072 + 1024 + 1023] = c.y;
        out0[(size_t)b * 3072 + 2048 + 1023] = c.z;
    }
}

// ---------------------------------------------------------------- ball query
// one wave per centroid; first-32-ascending-index semantics via ballot compaction
__global__ __launch_bounds__(256) void ballq_kernel(const float* __restrict__ xyz,
                                                    const float* __restrict__ out0,
                                                    int* __restrict__ idxbuf) {
    int wid = threadIdx.x >> 6, lane = threadIdx.x & 63;
    int m = blockIdx.x * 4 + wid;          // centroid id < 16384
    int b = m >> 10, s = m & 1023;
    const float* xb = xyz + (size_t)b * 3 * N_;
    double cx = (double)out0[b * 3072 + s];
    double cy = (double)out0[b * 3072 + 1024 + s];
    double cz = (double)out0[b * 3072 + 2048 + s];
    double c2 = cx * cx + cy * cy + cz * cz;
    const double rr = 0.4 * 0.4;
    int* ob = idxbuf + (size_t)m * K_;
    int cnt = 0, first = -1;
    for (int ch = 0; ch < N_ / 64; ++ch) {
        int i = ch * 64 + lane;
        double x = (double)xb[i], y = (double)xb[N_ + i], z = (double)xb[2 * N_ + i];
        double p2 = x * x + y * y + z * z;
        double dot = cx * x + cy * y + cz * z;
        double sqr = (c2 + p2) - 2.0 * dot;
        bool in = !(sqr > rr);
        unsigned long long mask = __ballot(in);
        if (in) {
            int pos = cnt + __popcll(mask & ((1ull << lane) - 1ull));
            if (pos < K_) ob[pos] = i;
        }
        if (cnt == 0 && mask) first = ch * 64 + (__ffsll((long long)mask) - 1);
        cnt += __popcll(mask);
        if (cnt >= K_) break;
    }
    if (cnt < K_ && lane >= cnt && lane < K_) ob[lane] = first;
}

// ---------------------------------------------------------------- gather + layer0 stats
__global__ __launch_bounds__(256) void gather_stats0(
        const float* __restrict__ xyz, const float* __restrict__ pts,
        const float* __restrict__ out0, const int* __restrict__ idxbuf,
        const float* __restrict__ W0, const float* __restrict__ b0,
        float* __restrict__ F, float2* __restrict__ part) {
    __shared__ float Fs[64][6];
    __shared__ float W0s[384];
    __shared__ float b0s[64];
    __shared__ float2 red[4][64];
    int tid = threadIdx.x;
    long rowbase = (long)blockIdx.x * 64;
    if (tid < 64) {
        long r = rowbase + tid;
        int b = (int)(r >> 15);
        int rem = (int)(r & 32767);
        int s = rem >> 5;
        int i = idxbuf[r];
        const float* xb = xyz + (size_t)b * 3 * N_;
        const float* pb = pts + (size_t)b * 3 * N_;
        float cx = out0[b * 3072 + s], cy = out0[b * 3072 + 1024 + s], cz = out0[b * 3072 + 2048 + s];
        float f[6];
        f[0] = xb[i] - cx; f[1] = xb[N_ + i] - cy; f[2] = xb[2 * N_ + i] - cz;
        f[3] = pb[i];      f[4] = pb[N_ + i];      f[5] = pb[2 * N_ + i];
        float* Fg = F + (size_t)r * 6;
#pragma unroll
        for (int c = 0; c < 6; ++c) { Fs[tid][c] = f[c]; Fg[c] = f[c]; }
        b0s[tid] = b0[tid];
    }
    for (int t = tid; t < 384; t += 256) W0s[t] = W0[t];
    __syncthreads();
    int o = tid & 63, rg = tid >> 6;
    float w[6];
#pragma unroll
    for (int c = 0; c < 6; ++c) w[c] = W0s[o * 6 + c];
    float sum = 0.f, sq = 0.f;
#pragma unroll
    for (int rr = 0; rr < 16; ++rr) {
        int rl = rg * 16 + rr;
        float y = b0s[o];
#pragma unroll
        for (int c = 0; c < 6; ++c) y += Fs[rl][c] * w[c];
        sum += y; sq += y * y;
    }
    red[rg][o] = make_float2(sum, sq);
    __syncthreads();
    if (tid < 64) {
        float2 t0 = red[0][tid], t1 = red[1][tid], t2 = red[2][tid], t3 = red[3][tid];
        part[(size_t)blockIdx.x * 64 + tid] =
            make_float2(t0.x + t1.x + t2.x + t3.x, t0.y + t1.y + t2.y + t3.y);
    }
}

// ---------------------------------------------------------------- BN stats reduce
__global__ __launch_bounds__(256) void reduce_stats(const float2* __restrict__ part,
                                                    int nblk, int C,
                                                    const float* __restrict__ g,
                                                    const float* __restrict__ beta,
                                                    float* __restrict__ scale,
                                                    float* __restrict__ shift) {
    int o = blockIdx.x;
    int tid = threadIdx.x;
    double s = 0.0, q = 0.0;
    for (int i = tid; i < nblk; i += 256) {
        float2 v = part[(size_t)i * C + o];
        s += (double)v.x; q += (double)v.y;
    }
    __shared__ double ss[256], qq[256];
    ss[tid] = s; qq[tid] = q;
    __syncthreads();
    for (int m = 128; m > 0; m >>= 1) {
        if (tid < m) { ss[tid] += ss[tid + m]; qq[tid] += qq[tid + m]; }
        __syncthreads();
    }
    if (tid == 0) {
        const double Rd = (double)R_;
        double mean = ss[0] / Rd;
        double var = qq[0] / Rd - mean * mean;
        double sc = (double)g[o] / sqrt(var + 1e-5);
        scale[o] = (float)sc;
        shift[o] = (float)((double)beta[o] - mean * sc);
    }
}

// ---------------------------------------------------------------- layer1 GEMM (recompute layer0 + BN0 + relu)
__global__ __launch_bounds__(256) void layer1_kernel(
        const float* __restrict__ F, const float* __restrict__ W0,
        const float* __restrict__ b0, const float* __restrict__ scale0,
        const float* __restrict__ shift0, const float* __restrict__ W1,
        const float* __restrict__ b1, float* __restrict__ Y1,
        float2* __restrict__ part) {
    __shared__ float Fs[64][6];
    __shared__ float W0s[384];
    __shared__ float b0s[64], sc0[64], sh0[64];
    __shared__ float Xs[64][68];
    __shared__ float W1s[64][68];
    __shared__ float2 red[16][64];
    int tid = threadIdx.x;
    long rowbase = (long)blockIdx.x * 64;
    for (int t = tid; t < 384; t += 256) { Fs[t / 6][t % 6] = F[rowbase * 6 + t]; W0s[t] = W0[t]; }
    if (tid < 64) { b0s[tid] = b0[tid]; sc0[tid] = scale0[tid]; sh0[tid] = shift0[tid]; }
    for (int t = tid; t < 4096; t += 256) { int o = t >> 6, c = t & 63; W1s[c][o] = W1[t]; }
    __syncthreads();
    {
        int o = tid & 63, rg = tid >> 6;
        float w[6];
#pragma unroll
        for (int c = 0; c < 6; ++c) w[c] = W0s[o * 6 + c];
        float sc = sc0[o], sh = sh0[o], bb = b0s[o];
#pragma unroll
        for (int rr = 0; rr < 16; ++rr) {
            int rl = rg * 16 + rr;
            float y = bb;
#pragma unroll
            for (int c = 0; c < 6; ++c) y += Fs[rl][c] * w[c];
            Xs[rl][o] = fmaxf(sc * y + sh, 0.f);
        }
    }
    __syncthreads();
    int cg = tid & 15, rgp = tid >> 4;   // cols cg*4.., rows rgp*4..
    float acc[4][4] = {};
    for (int c = 0; c < 64; ++c) {
        float xr[4];
#pragma unroll
        for (int rr = 0; rr < 4; ++rr) xr[rr] = Xs[rgp * 4 + rr][c];
        float4 wv = *(const float4*)&W1s[c][cg * 4];
#pragma unroll
        for (int rr = 0; rr < 4; ++rr) {
            acc[rr][0] += xr[rr] * wv.x; acc[rr][1] += xr[rr] * wv.y;
            acc[rr][2] += xr[rr] * wv.z; acc[rr][3] += xr[rr] * wv.w;
        }
    }
    float bb1[4];
#pragma unroll
    for (int cc = 0; cc < 4; ++cc) bb1[cc] = b1[cg * 4 + cc];
#pragma unroll
    for (int rr = 0; rr < 4; ++rr)
#pragma unroll
        for (int cc = 0; cc < 4; ++cc) acc[rr][cc] += bb1[cc];
    // write Y1
#pragma unroll
    for (int rr = 0; rr < 4; ++rr) {
        long r = rowbase + rgp * 4 + rr;
        float4 v = make_float4(acc[rr][0], acc[rr][1], acc[rr][2], acc[rr][3]);
        *(float4*)&Y1[r * 64 + cg * 4] = v;
    }
    // stats
#pragma unroll
    for (int cc = 0; cc < 4; ++cc) {
        float s = acc[0][cc] + acc[1][cc] + acc[2][cc] + acc[3][cc];
        float q = acc[0][cc] * acc[0][cc] + acc[1][cc] * acc[1][cc] +
                  acc[2][cc] * acc[2][cc] + acc[3][cc] * acc[3][cc];
        red[rgp][cg * 4 + cc] = make_float2(s, q);
    }
    __syncthreads();
    if (tid < 64) {
        float s = 0.f, q = 0.f;
#pragma unroll
        for (int rp = 0; rp < 16; ++rp) { float2 v = red[rp][tid]; s += v.x; q += v.y; }
        part[(size_t)blockIdx.x * 64 + tid] = make_float2(s, q);
    }
}

// ---------------------------------------------------------------- layer2 GEMM + per-(b,s) max/min + stats
__global__ __launch_bounds__(256) void layer2_kernel(
        const float* __restrict__ Y1, const float* __restrict__ scale1,
        const float* __restrict__ shift1, const float* __restrict__ W2,
        const float* __restrict__ b2, float* __restrict__ gmax,
        float* __restrict__ gmin, float2* __restrict__ part) {
    __shared__ float Xs[64][68];
    __shared__ float W2s[64][132];
    __shared__ float red[16][128];
    int tid = threadIdx.x;
    long rowbase = (long)blockIdx.x * 64;
    {
        int o = tid & 63, rg = tid >> 6;
        float sc = scale1[o], sh = shift1[o];
#pragma unroll
        for (int rr = 0; rr < 16; ++rr) {
            int rl = rg * 16 + rr;
            float y = Y1[(rowbase + rl) * 64 + o];
            Xs[rl][o] = fmaxf(sc * y + sh, 0.f);
        }
    }
    for (int t = tid; t < 8192; t += 256) { int o = t >> 6, c = t & 63; W2s[c][o] = W2[t]; }
    __syncthreads();
    int cg = tid & 15, rgp = tid >> 4;   // cols cg*8.., rows rgp*4..
    float acc[4][8] = {};
    for (int c = 0; c < 64; ++c) {
        float xr[4];
#pragma unroll
        for (int rr = 0; rr < 4; ++rr) xr[rr] = Xs[rgp * 4 + rr][c];
        float4 wa = *(const float4*)&W2s[c][cg * 8];
        float4 wb = *(const float4*)&W2s[c][cg * 8 + 4];
#pragma unroll
        for (int rr = 0; rr < 4; ++rr) {
            acc[rr][0] += xr[rr] * wa.x; acc[rr][1] += xr[rr] * wa.y;
            acc[rr][2] += xr[rr] * wa.z; acc[rr][3] += xr[rr] * wa.w;
            acc[rr][4] += xr[rr] * wb.x; acc[rr][5] += xr[rr] * wb.y;
            acc[rr][6] += xr[rr] * wb.z; acc[rr][7] += xr[rr] * wb.w;
        }
    }
#pragma unroll
    for (int j = 0; j < 8; ++j) {
        float bb = b2[cg * 8 + j];
#pragma unroll
        for (int rr = 0; rr < 4; ++rr) acc[rr][j] += bb;
    }
    // ---- pass 1: sum
#pragma unroll
    for (int j = 0; j < 8; ++j)
        red[rgp][cg * 8 + j] = acc[0][j] + acc[1][j] + acc[2][j] + acc[3][j];
    __syncthreads();
    float psum = 0.f;
    if (tid < 128) { for (int rp = 0; rp < 16; ++rp) psum += red[rp][tid]; }
    __syncthreads();
    // ---- pass 2: sumsq
#pragma unroll
    for (int j = 0; j < 8; ++j)
        red[rgp][cg * 8 + j] = acc[0][j] * acc[0][j] + acc[1][j] * acc[1][j] +
                               acc[2][j] * acc[2][j] + acc[3][j] * acc[3][j];
    __syncthreads();
    if (tid < 128) {
        float psq = 0.f;
        for (int rp = 0; rp < 16; ++rp) psq += red[rp][tid];
        part[(size_t)blockIdx.x * 128 + tid] = make_float2(psum, psq);
    }
    __syncthreads();
    // ---- pass 3: max (rows of one thread all lie in one k-group)
#pragma unroll
    for (int j = 0; j < 8; ++j)
        red[rgp][cg * 8 + j] = fmaxf(fmaxf(acc[0][j], acc[1][j]), fmaxf(acc[2][j], acc[3][j]));
    __syncthreads();
    {
        int gsel = tid >> 7, col = tid & 127;
        float mv = -3.0e38f;
        for (int rp = gsel * 8; rp < gsel * 8 + 8; ++rp) mv = fmaxf(mv, red[rp][col]);
        gmax[((size_t)blockIdx.x * 2 + gsel) * 128 + col] = mv;
    }
    __syncthreads();
    // ---- pass 4: min
#pragma unroll
    for (int j = 0; j < 8; ++j)
        red[rgp][cg * 8 + j] = fminf(fminf(acc[0][j], acc[1][j]), fminf(acc[2][j], acc[3][j]));
    __syncthreads();
    {
        int gsel = tid >> 7, col = tid & 127;
        float mv = 3.0e38f;
        for (int rp = gsel * 8; rp < gsel * 8 + 8; ++rp) mv = fminf(mv, red[rp][col]);
        gmin[((size_t)blockIdx.x * 2 + gsel) * 128 + col] = mv;
    }
}

// ---------------------------------------------------------------- final BN2 + relu + transpose
__global__ __launch_bounds__(256) void final_kernel(const float* __restrict__ gmax,
                                                    const float* __restrict__ gmin,
                                                    const float* __restrict__ scale2,
                                                    const float* __restrict__ shift2,
                                                    float* __restrict__ out1) {
    int b = blockIdx.x, st = blockIdx.y, ot = blockIdx.z;
    __shared__ float tile[32][33];
    int tid = threadIdx.x;
    for (int e = tid; e < 1024; e += 256) {
        int sl = e >> 5, ol = e & 31;
        int s = st * 32 + sl, o = ot * 32 + ol;
        size_t m = (size_t)b * 1024 + s;
        float sc = scale2[o];
        float v = (sc >= 0.f) ? gmax[m * 128 + o] : gmin[m * 128 + o];
        tile[sl][ol] = fmaxf(sc * v + shift2[o], 0.f);
    }
    __syncthreads();
    for (int e = tid; e < 1024; e += 256) {
        int ol = e >> 5, sl = e & 31;
        int s = st * 32 + sl, o = ot * 32 + ol;
        out1[(size_t)b * 131072 + (size_t)o * 1024 + s] = tile[sl][ol];
    }
}

// ---------------------------------------------------------------- launch
extern "C" void kernel_launch(void* const* d_in, const int* in_sizes, int n_in,
                              void* d_out, int out_size, void* d_ws, size_t ws_size,
                              hipStream_t stream) {
    const float* xyz   = (const float*)d_in[0];
    const float* pts   = (const float*)d_in[1];
    const float* W0    = (const float*)d_in[2];
    const float* b0    = (const float*)d_in[3];
    const float* g0    = (const float*)d_in[4];
    const float* beta0 = (const float*)d_in[5];
    const float* W1    = (const float*)d_in[6];
    const float* b1    = (const float*)d_in[7];
    const float* g1    = (const float*)d_in[8];
    const float* beta1 = (const float*)d_in[9];
    const float* W2    = (const float*)d_in[10];
    const float* b2    = (const float*)d_in[11];
    const float* g2    = (const float*)d_in[12];
    const float* beta2 = (const float*)d_in[13];

    float* out0 = (float*)d_out;                  // (B,3,1024)  = 49152
    float* out1 = (float*)d_out + 49152;          // (B,128,1024)

    char* w = (char*)d_ws;
    size_t off = 0;
    int*    idxbuf = (int*)(w + off);    off += (size_t)R_ * 4;
    float*  F      = (float*)(w + off);  off += (size_t)R_ * 6 * 4;
    float*  Y1     = (float*)(w + off);  off += (size_t)R_ * 64 * 4;
    float*  gmax   = (float*)(w + off);  off += (size_t)B_ * S_ * 128 * 4;
    float*  gmin   = (float*)(w + off);  off += (size_t)B_ * S_ * 128 * 4;
    float2* part   = (float2*)(w + off); off += (size_t)NBLK_ * 128 * 2 * 4;
    float*  ss     = (float*)(w + off);  off += 512 * 4;
    float* scale0 = ss,       *shift0 = ss + 64;
    float* scale1 = ss + 128, *shift1 = ss + 192;
    float* scale2 = ss + 256, *shift2 = ss + 384;

    fps_kernel<<<B_, 512, 0, stream>>>(xyz, out0);
    ballq_kernel<<<(B_ * S_) / 4, 256, 0, stream>>>(xyz, out0, idxbuf);
    gather_stats0<<<NBLK_, 256, 0, stream>>>(xyz, pts, out0, idxbuf, W0, b0, F, part);
    reduce_stats<<<64, 256, 0, stream>>>(part, NBLK_, 64, g0, beta0, scale0, shift0);
    layer1_kernel<<<NBLK_, 256, 0, stream>>>(F, W0, b0, scale0, shift0, W1, b1, Y1, part);
    reduce_stats<<<64, 256, 0, stream>>>(part, NBLK_, 64, g1, beta1, scale1, shift1);
    layer2_kernel<<<NBLK_, 256, 0, stream>>>(Y1, scale1, shift1, W2, b2, gmax, gmin, part);
    reduce_stats<<<128, 256, 0, stream>>>(part, NBLK_, 128, g2, beta2, scale2, shift2);
    final_kernel<<<dim3(B_, 32, 4), 256, 0, stream>>>(gmax, gmin, scale2, shift2, out1);
}

// Round 6
// 857.860 us; speedup vs baseline: 1.4896x; 1.4896x over previous
//
#include <hip/hip_runtime.h>
#include <hip/hip_bf16.h>

#define B_ 16
#define N_ 4096
#define S_ 1024
#define K_ 32
#define R_ (B_*S_*K_)   // 524288 rows
#define NBLK_ (R_/64)   // 8192 row-tiles of 64

typedef unsigned short u16;
typedef __attribute__((ext_vector_type(8))) short bf16x8;
typedef __attribute__((ext_vector_type(4))) float f32x4;

__device__ __forceinline__ u16 f2bf(float f) {
    __hip_bfloat16 h = __float2bfloat16(f);
    return __builtin_bit_cast(u16, h);
}
__device__ __forceinline__ float bf2f(u16 u) {
    unsigned x = ((unsigned)u) << 16;
    return __builtin_bit_cast(float, x);
}

// fmax(v, dpp_move<CTRL>(v)) on f64; identity-preserving (old=own, bound_ctrl=0).
template <int CTRL>
__device__ __forceinline__ double dpp_max_f64(double v) {
    unsigned long long b = (unsigned long long)__double_as_longlong(v);
    int lo = (int)(unsigned)b;
    int hi = (int)(unsigned)(b >> 32);
    int olo = __builtin_amdgcn_update_dpp(lo, lo, CTRL, 0xF, 0xF, false);
    int ohi = __builtin_amdgcn_update_dpp(hi, hi, CTRL, 0xF, 0xF, false);
    double o = __longlong_as_double(
        (long long)(((unsigned long long)(unsigned)ohi << 32) | (unsigned)olo));
    return fmax(v, o);
}

// replace low 12 mantissa bits of positive double with idx (order-preserving key)
__device__ __forceinline__ double packd(double d, int idx) {
    unsigned long long b = (unsigned long long)__double_as_longlong(d);
    b = (b & ~0xFFFull) | (unsigned)idx;
    return __longlong_as_double((long long)b);
}

// ---------------------------------------------------------------- FPS
// one block per batch, 512 threads (8 waves), 8 points/thread, f64 distances
// (+1.0 biased, so all values positive). dist[] stores PACKED keys (idx in low
// 12 mantissa bits) -> per-iter tree is 7 v_max_f64, butterfly is
// update_dpp x2 + v_max_f64 per level. out0 written in epilogue from recorded
// far history (2 regs/thread).
__global__ __launch_bounds__(512, 2) void fps_kernel(const float* __restrict__ xyz,
                                                     float* __restrict__ out0) {
    const int b = blockIdx.x;
    const int tid = threadIdx.x;
    const int lane = tid & 63, wid = tid >> 6;       // 8 waves
    __shared__ float4 p4[N_];
    __shared__ double candd[2][8];
    const float* xb = xyz + (size_t)b * 3 * N_;

    double x64[8], y64[8], z64[8], q64[8], dist[8];
#pragma unroll
    for (int j = 0; j < 8; ++j) {
        int i = tid + j * 512;
        float x = xb[i], y = xb[N_ + i], z = xb[2 * N_ + i];
        p4[i] = make_float4(x, y, z, 0.f);
        x64[j] = (double)x; y64[j] = (double)y; z64[j] = (double)z;
        q64[j] = x64[j] * x64[j] + y64[j] * y64[j] + z64[j] * z64[j];
        dist[j] = 1e30;
    }
    __syncthreads();

    int far = 0;
    int f0 = 0, f1 = 0;
    for (int s = 0; s < 1023; ++s) {
        float4 c = p4[far];
        f0 = (tid == s) ? far : f0;
        f1 = (tid + 512 == s) ? far : f1;
        double cx = (double)c.x, cy = (double)c.y, cz = (double)c.z;
        double c2p = cx * cx + cy * cy + cz * cz + 1.0;
        double A = -2.0 * cx, Bc = -2.0 * cy, Cc = -2.0 * cz;
#pragma unroll
        for (int j = 0; j < 8; ++j) {
            double d = fma(A, x64[j], fma(Bc, y64[j], fma(Cc, z64[j], q64[j] + c2p)));
            dist[j] = fmin(dist[j], packd(d, tid | (j << 9)));
        }
        double k = fmax(fmax(fmax(dist[0], dist[1]), fmax(dist[2], dist[3])),
                        fmax(fmax(dist[4], dist[5]), fmax(dist[6], dist[7])));
        k = dpp_max_f64<0x111>(k);   // row_shr:1
        k = dpp_max_f64<0x112>(k);   // row_shr:2
        k = dpp_max_f64<0x114>(k);   // row_shr:4
        k = dpp_max_f64<0x118>(k);   // row_shr:8
        k = dpp_max_f64<0x142>(k);   // row_bcast15
        k = dpp_max_f64<0x143>(k);   // row_bcast31
        int buf = s & 1;
        if (lane == 63) candd[buf][wid] = k;
        __syncthreads();
        double k2 = candd[buf][lane & 7];
        k2 = dpp_max_f64<0xB1>(k2);      // quad_perm xor1
        k2 = dpp_max_f64<0x4E>(k2);      // quad_perm xor2
        k2 = dpp_max_f64<0x124>(k2);     // row_ror:4 (8-periodic -> lane0 global)
        unsigned lo = (unsigned)(unsigned long long)__double_as_longlong(k2);
        far = (int)(__builtin_amdgcn_readfirstlane(lo) & 0xFFFu);
    }
    if (tid == 511) f1 = far;
    {
        float4 c0 = p4[f0];
        out0[(size_t)b * 3072 + tid]        = c0.x;
        out0[(size_t)b * 3072 + 1024 + tid] = c0.y;
        out0[(size_t)b * 3072 + 2048 + tid] = c0.z;
        float4 c1 = p4[f1];
        out0[(size_t)b * 3072 + 512 + tid]        = c1.x;
        out0[(size_t)b * 3072 + 1024 + 512 + tid] = c1.y;
        out0[(size_t)b * 3072 + 2048 + 512 + tid] = c1.z;
    }
}

// ---------------------------------------------------------------- ball query
__global__ __launch_bounds__(256) void ballq_kernel(const float* __restrict__ xyz,
                                                    const float* __restrict__ out0,
                                                    int* __restrict__ idxbuf) {
    int wid = threadIdx.x >> 6, lane = threadIdx.x & 63;
    int m = blockIdx.x * 4 + wid;          // centroid id < 16384
    int b = m >> 10, s = m & 1023;
    const float* xb = xyz + (size_t)b * 3 * N_;
    double cx = (double)out0[b * 3072 + s];
    double cy = (double)out0[b * 3072 + 1024 + s];
    double cz = (double)out0[b * 3072 + 2048 + s];
    double c2 = cx * cx + cy * cy + cz * cz;
    const double rr = 0.4 * 0.4;
    int* ob = idxbuf + (size_t)m * K_;
    int cnt = 0, first = -1;
    for (int ch = 0; ch < N_ / 64; ++ch) {
        int i = ch * 64 + lane;
        double x = (double)xb[i], y = (double)xb[N_ + i], z = (double)xb[2 * N_ + i];
        double p2 = x * x + y * y + z * z;
        double dot = cx * x + cy * y + cz * z;
        double sqr = (c2 + p2) - 2.0 * dot;
        bool in = !(sqr > rr);
        unsigned long long mask = __ballot(in);
        if (in) {
            int pos = cnt + __popcll(mask & ((1ull << lane) - 1ull));
            if (pos < K_) ob[pos] = i;
        }
        if (cnt == 0 && mask) first = ch * 64 + (__ffsll((long long)mask) - 1);
        cnt += __popcll(mask);
        if (cnt >= K_) break;
    }
    if (cnt < K_ && lane >= cnt && lane < K_) ob[lane] = first;
}

// ---------------------------------------------------------------- gather + layer0 stats
__global__ __launch_bounds__(256) void gather_stats0(
        const float* __restrict__ xyz, const float* __restrict__ pts,
        const float* __restrict__ out0, const int* __restrict__ idxbuf,
        const float* __restrict__ W0, const float* __restrict__ b0,
        float* __restrict__ F, float2* __restrict__ part) {
    __shared__ float Fs[64][6];
    __shared__ float W0s[384];
    __shared__ float b0s[64];
    __shared__ float2 red[4][64];
    int tid = threadIdx.x;
    long rowbase = (long)blockIdx.x * 64;
    if (tid < 64) {
        long r = rowbase + tid;
        int b = (int)(r >> 15);
        int rem = (int)(r & 32767);
        int s = rem >> 5;
        int i = idxbuf[r];
        const float* xb = xyz + (size_t)b * 3 * N_;
        const float* pb = pts + (size_t)b * 3 * N_;
        float cx = out0[b * 3072 + s], cy = out0[b * 3072 + 1024 + s], cz = out0[b * 3072 + 2048 + s];
        float f[6];
        f[0] = xb[i] - cx; f[1] = xb[N_ + i] - cy; f[2] = xb[2 * N_ + i] - cz;
        f[3] = pb[i];      f[4] = pb[N_ + i];      f[5] = pb[2 * N_ + i];
        float* Fg = F + (size_t)r * 6;
#pragma unroll
        for (int c = 0; c < 6; ++c) { Fs[tid][c] = f[c]; Fg[c] = f[c]; }
        b0s[tid] = b0[tid];
    }
    for (int t = tid; t < 384; t += 256) W0s[t] = W0[t];
    __syncthreads();
    int o = tid & 63, rg = tid >> 6;
    float w[6];
#pragma unroll
    for (int c = 0; c < 6; ++c) w[c] = W0s[o * 6 + c];
    float sum = 0.f, sq = 0.f;
#pragma unroll
    for (int rr = 0; rr < 16; ++rr) {
        int rl = rg * 16 + rr;
        float y = b0s[o];
#pragma unroll
        for (int c = 0; c < 6; ++c) y += Fs[rl][c] * w[c];
        sum += y; sq += y * y;
    }
    red[rg][o] = make_float2(sum, sq);
    __syncthreads();
    if (tid < 64) {
        float2 t0 = red[0][tid], t1 = red[1][tid], t2 = red[2][tid], t3 = red[3][tid];
        part[(size_t)blockIdx.x * 64 + tid] =
            make_float2(t0.x + t1.x + t2.x + t3.x, t0.y + t1.y + t2.y + t3.y);
    }
}

// ---------------------------------------------------------------- BN stats reduce
__global__ __launch_bounds__(256) void reduce_stats(const float2* __restrict__ part,
                                                    int nblk, int C,
                                                    const float* __restrict__ g,
                                                    const float* __restrict__ beta,
                                                    float* __restrict__ scale,
                                                    float* __restrict__ shift) {
    int o = blockIdx.x;
    int tid = threadIdx.x;
    double s = 0.0, q = 0.0;
    for (int i = tid; i < nblk; i += 256) {
        float2 v = part[(size_t)i * C + o];
        s += (double)v.x; q += (double)v.y;
    }
    __shared__ double ss[256], qq[256];
    ss[tid] = s; qq[tid] = q;
    __syncthreads();
    for (int m = 128; m > 0; m >>= 1) {
        if (tid < m) { ss[tid] += ss[tid + m]; qq[tid] += qq[tid + m]; }
        __syncthreads();
    }
    if (tid == 0) {
        const double Rd = (double)R_;
        double mean = ss[0] / Rd;
        double var = qq[0] / Rd - mean * mean;
        double sc = (double)g[o] / sqrt(var + 1e-5);
        scale[o] = (float)sc;
        shift[o] = (float)((double)beta[o] - mean * sc);
    }
}

// ---------------------------------------------------------------- weight f32->bf16 prologue
__global__ __launch_bounds__(256) void cvt_w_kernel(const float* __restrict__ W1,
                                                    const float* __restrict__ W2,
                                                    u16* __restrict__ W1bf,
                                                    u16* __restrict__ W2bf) {
    int t = blockIdx.x * 256 + threadIdx.x;    // grid = 32 blocks -> t < 8192
    if (t < 4096) W1bf[t] = f2bf(W1[t]);
    W2bf[t] = f2bf(W2[t]);
}

// ---------------------------------------------------------------- layer1: recompute layer0+BN0+relu -> bf16 MFMA GEMM (64x64) -> Y1 bf16 + stats
__global__ __launch_bounds__(256) void layer1_mfma(
        const float* __restrict__ F, const float* __restrict__ W0,
        const float* __restrict__ b0, const float* __restrict__ scale0,
        const float* __restrict__ shift0, const u16* __restrict__ W1bf,
        const float* __restrict__ b1, u16* __restrict__ Y1bf,
        float2* __restrict__ part) {
    __shared__ float Fs[64][6];
    __shared__ float W0s[384];
    __shared__ float b0s[64], sc0[64], sh0[64];
    __shared__ u16 Xs[64][72];
    __shared__ float ssum[16][64];
    __shared__ float ssq[16][64];
    int tid = threadIdx.x;
    long rowbase = (long)blockIdx.x * 64;
    for (int t = tid; t < 384; t += 256) { Fs[t / 6][t % 6] = F[rowbase * 6 + t]; W0s[t] = W0[t]; }
    if (tid < 64) { b0s[tid] = b0[tid]; sc0[tid] = scale0[tid]; sh0[tid] = shift0[tid]; }
    __syncthreads();
    {   // X1 = relu(bn0(F W0^T + b0)) -> bf16 tile
        int o = tid & 63, rg = tid >> 6;
        float w[6];
#pragma unroll
        for (int c = 0; c < 6; ++c) w[c] = W0s[o * 6 + c];
        float sc = sc0[o], sh = sh0[o], bb = b0s[o];
#pragma unroll
        for (int rr = 0; rr < 16; ++rr) {
            int rl = rg * 16 + rr;
            float y = bb;
#pragma unroll
            for (int c = 0; c < 6; ++c) y += Fs[rl][c] * w[c];
            Xs[rl][o] = f2bf(fmaxf(sc * y + sh, 0.f));
        }
    }
    __syncthreads();
    int l = tid & 63, w = tid >> 6;
    int ar = l & 15, kg = l >> 4;     // A row / k-group (also C col / row-group)
    bf16x8 a0 = *(const bf16x8*)&Xs[w * 16 + ar][kg * 8];
    bf16x8 a1 = *(const bf16x8*)&Xs[w * 16 + ar][32 + kg * 8];
    f32x4 acc[4];
#pragma unroll
    for (int t4 = 0; t4 < 4; ++t4) acc[t4] = (f32x4){0.f, 0.f, 0.f, 0.f};
#pragma unroll
    for (int t4 = 0; t4 < 4; ++t4) {
        const u16* wp = &W1bf[(t4 * 16 + ar) * 64 + kg * 8];
        bf16x8 bfr0 = *(const bf16x8*)wp;
        bf16x8 bfr1 = *(const bf16x8*)(wp + 32);
        acc[t4] = __builtin_amdgcn_mfma_f32_16x16x32_bf16(a0, bfr0, acc[t4], 0, 0, 0);
        acc[t4] = __builtin_amdgcn_mfma_f32_16x16x32_bf16(a1, bfr1, acc[t4], 0, 0, 0);
    }
#pragma unroll
    for (int t4 = 0; t4 < 4; ++t4) {
        int col = t4 * 16 + ar;
        float bb = b1[col];
        float s = 0.f, q = 0.f;
#pragma unroll
        for (int r = 0; r < 4; ++r) {
            float y = acc[t4][r] + bb;
            int row = w * 16 + kg * 4 + r;
            Y1bf[(rowbase + row) * 64 + col] = f2bf(y);
            s += y; q += y * y;
        }
        ssum[w * 4 + kg][col] = s;
        ssq[w * 4 + kg][col] = q;
    }
    __syncthreads();
    if (tid < 64) {
        float s = 0.f, q = 0.f;
#pragma unroll
        for (int i = 0; i < 16; ++i) { s += ssum[i][tid]; q += ssq[i][tid]; }
        part[(size_t)blockIdx.x * 64 + tid] = make_float2(s, q);
    }
}

// ---------------------------------------------------------------- layer2: BN1+relu -> bf16 MFMA GEMM (64x128) -> per-sample max/min + stats
__global__ __launch_bounds__(256) void layer2_mfma(
        const u16* __restrict__ Y1bf, const float* __restrict__ scale1,
        const float* __restrict__ shift1, const u16* __restrict__ W2bf,
        const float* __restrict__ b2, float* __restrict__ gmax,
        float* __restrict__ gmin, float2* __restrict__ part) {
    __shared__ u16 Xs[64][72];
    __shared__ float sc1s[64], sh1s[64];
    __shared__ float mxs[16][128], mns[16][128];
    __shared__ float ssum[16][128], ssq[16][128];
    int tid = threadIdx.x;
    long rowbase = (long)blockIdx.x * 64;
    if (tid < 64) { sc1s[tid] = scale1[tid]; sh1s[tid] = shift1[tid]; }
    __syncthreads();
    {   // X2 = relu(bn1(Y1)) -> bf16 tile; vectorized bf16 loads
        int r = tid >> 2, seg = (tid & 3) * 16;
        const u16* yp = &Y1bf[(rowbase + r) * 64 + seg];
        bf16x8 v0 = *(const bf16x8*)yp;
        bf16x8 v1 = *(const bf16x8*)(yp + 8);
#pragma unroll
        for (int j = 0; j < 8; ++j) {
            float x0 = fmaxf(sc1s[seg + j] * bf2f((u16)v0[j]) + sh1s[seg + j], 0.f);
            float x1 = fmaxf(sc1s[seg + 8 + j] * bf2f((u16)v1[j]) + sh1s[seg + 8 + j], 0.f);
            Xs[r][seg + j] = f2bf(x0);
            Xs[r][seg + 8 + j] = f2bf(x1);
        }
    }
    __syncthreads();
    int l = tid & 63, w = tid >> 6;
    int ar = l & 15, kg = l >> 4;
    bf16x8 a0 = *(const bf16x8*)&Xs[w * 16 + ar][kg * 8];
    bf16x8 a1 = *(const bf16x8*)&Xs[w * 16 + ar][32 + kg * 8];
    f32x4 acc[8];
#pragma unroll
    for (int t8 = 0; t8 < 8; ++t8) acc[t8] = (f32x4){0.f, 0.f, 0.f, 0.f};
#pragma unroll
    for (int t8 = 0; t8 < 8; ++t8) {
        const u16* wp = &W2bf[(t8 * 16 + ar) * 64 + kg * 8];
        bf16x8 bfr0 = *(const bf16x8*)wp;
        bf16x8 bfr1 = *(const bf16x8*)(wp + 32);
        acc[t8] = __builtin_amdgcn_mfma_f32_16x16x32_bf16(a0, bfr0, acc[t8], 0, 0, 0);
        acc[t8] = __builtin_amdgcn_mfma_f32_16x16x32_bf16(a1, bfr1, acc[t8], 0, 0, 0);
    }
#pragma unroll
    for (int t8 = 0; t8 < 8; ++t8) {
        int col = t8 * 16 + ar;
        float bb = b2[col];
        float y0 = acc[t8][0] + bb, y1 = acc[t8][1] + bb;
        float y2 = acc[t8][2] + bb, y3 = acc[t8][3] + bb;
        ssum[w * 4 + kg][col] = y0 + y1 + y2 + y3;
        ssq[w * 4 + kg][col] = y0 * y0 + y1 * y1 + y2 * y2 + y3 * y3;
        mxs[w * 4 + kg][col] = fmaxf(fmaxf(y0, y1), fmaxf(y2, y3));
        mns[w * 4 + kg][col] = fminf(fminf(y0, y1), fminf(y2, y3));
    }
    __syncthreads();
    if (tid < 128) {
        int col = tid;
        float s = 0.f, q = 0.f;
        float m0 = -3.0e38f, m1 = -3.0e38f, n0 = 3.0e38f, n1 = 3.0e38f;
#pragma unroll
        for (int i = 0; i < 8; ++i) {
            s += ssum[i][col]; q += ssq[i][col];
            m0 = fmaxf(m0, mxs[i][col]); n0 = fminf(n0, mns[i][col]);
        }
#pragma unroll
        for (int i = 8; i < 16; ++i) {
            s += ssum[i][col]; q += ssq[i][col];
            m1 = fmaxf(m1, mxs[i][col]); n1 = fminf(n1, mns[i][col]);
        }
        part[(size_t)blockIdx.x * 128 + col] = make_float2(s, q);
        gmax[((size_t)blockIdx.x * 2 + 0) * 128 + col] = m0;
        gmax[((size_t)blockIdx.x * 2 + 1) * 128 + col] = m1;
        gmin[((size_t)blockIdx.x * 2 + 0) * 128 + col] = n0;
        gmin[((size_t)blockIdx.x * 2 + 1) * 128 + col] = n1;
    }
}

// ---------------------------------------------------------------- final BN2 + relu + transpose
__global__ __launch_bounds__(256) void final_kernel(const float* __restrict__ gmax,
                                                    const float* __restrict__ gmin,
                                                    const float* __restrict__ scale2,
                                                    const float* __restrict__ shift2,
                                                    float* __restrict__ out1) {
    int b = blockIdx.x, st = blockIdx.y, ot = blockIdx.z;
    __shared__ float tile[32][33];
    int tid = threadIdx.x;
    for (int e = tid; e < 1024; e += 256) {
        int sl = e >> 5, ol = e & 31;
        int s = st * 32 + sl, o = ot * 32 + ol;
        size_t m = (size_t)b * 1024 + s;
        float sc = scale2[o];
        float v = (sc >= 0.f) ? gmax[m * 128 + o] : gmin[m * 128 + o];
        tile[sl][ol] = fmaxf(sc * v + shift2[o], 0.f);
    }
    __syncthreads();
    for (int e = tid; e < 1024; e += 256) {
        int ol = e >> 5, sl = e & 31;
        int s = st * 32 + sl, o = ot * 32 + ol;
        out1[(size_t)b * 131072 + (size_t)o * 1024 + s] = tile[sl][ol];
    }
}

// ---------------------------------------------------------------- launch
extern "C" void kernel_launch(void* const* d_in, const int* in_sizes, int n_in,
                              void* d_out, int out_size, void* d_ws, size_t ws_size,
                              hipStream_t stream) {
    const float* xyz   = (const float*)d_in[0];
    const float* pts   = (const float*)d_in[1];
    const float* W0    = (const float*)d_in[2];
    const float* b0    = (const float*)d_in[3];
    const float* g0    = (const float*)d_in[4];
    const float* beta0 = (const float*)d_in[5];
    const float* W1    = (const float*)d_in[6];
    const float* b1    = (const float*)d_in[7];
    const float* g1    = (const float*)d_in[8];
    const float* beta1 = (const float*)d_in[9];
    const float* W2    = (const float*)d_in[10];
    const float* b2    = (const float*)d_in[11];
    const float* g2    = (const float*)d_in[12];
    const float* beta2 = (const float*)d_in[13];

    float* out0 = (float*)d_out;                  // (B,3,1024)  = 49152
    float* out1 = (float*)d_out + 49152;          // (B,128,1024)

    char* w = (char*)d_ws;
    size_t off = 0;
    int*    idxbuf = (int*)(w + off);    off += (size_t)R_ * 4;
    float*  F      = (float*)(w + off);  off += (size_t)R_ * 6 * 4;
    u16*    Y1bf   = (u16*)(w + off);    off += (size_t)R_ * 64 * 2;
    float*  gmax   = (float*)(w + off);  off += (size_t)B_ * S_ * 128 * 4;
    float*  gmin   = (float*)(w + off);  off += (size_t)B_ * S_ * 128 * 4;
    float2* part   = (float2*)(w + off); off += (size_t)NBLK_ * 128 * 2 * 4;
    u16*    W1bf   = (u16*)(w + off);    off += 4096 * 2;
    u16*    W2bf   = (u16*)(w + off);    off += 8192 * 2;
    float*  ss     = (float*)(w + off);  off += 512 * 4;
    float* scale0 = ss,       *shift0 = ss + 64;
    float* scale1 = ss + 128, *shift1 = ss + 192;
    float* scale2 = ss + 256, *shift2 = ss + 384;

    cvt_w_kernel<<<32, 256, 0, stream>>>(W1, W2, W1bf, W2bf);
    fps_kernel<<<B_, 512, 0, stream>>>(xyz, out0);
    ballq_kernel<<<(B_ * S_) / 4, 256, 0, stream>>>(xyz, out0, idxbuf);
    gather_stats0<<<NBLK_, 256, 0, stream>>>(xyz, pts, out0, idxbuf, W0, b0, F, part);
    reduce_stats<<<64, 256, 0, stream>>>(part, NBLK_, 64, g0, beta0, scale0, shift0);
    layer1_mfma<<<NBLK_, 256, 0, stream>>>(F, W0, b0, scale0, shift0, W1bf, b1, Y1bf, part);
    reduce_stats<<<64, 256, 0, stream>>>(part, NBLK_, 64, g1, beta1, scale1, shift1);
    layer2_mfma<<<NBLK_, 256, 0, stream>>>(Y1bf, scale1, shift1, W2bf, b2, gmax, gmin, part);
    reduce_stats<<<128, 256, 0, stream>>>(part, NBLK_, 128, g2, beta2, scale2, shift2);
    final_kernel<<<dim3(B_, 32, 4), 256, 0, stream>>>(gmax, gmin, scale2, shift2, out1);
}